// Round 5
// baseline (207.041 us; speedup 1.0000x reference)
//
#include <hip/hip_runtime.h>

#define NEG_SLOPE 0.04f
#define MASK_VAL  -9.0e15f

namespace {
constexpr int Bz   = 128;  // batch
constexpr int NN   = 64;   // nodes (1 robot + 63 humans)
constexpr int RDim = 9;
constexpr int HDim = 5;
constexpr int HIDv = 64;
constexpr int XDv  = 128;  // node embedding dim
}

// ---------------------------------------------------------------------------
// Kernel 1: node embeddings.  4 blocks per batch (16 nodes each) -> 512 blocks.
//   robot:  [B,1,9]  -> MLP 9->64 relu ->64->128 relu
//   humans: [B,63,5] -> MLP 5->64 relu ->64->128 relu
//   X out:  [B,64,128]
// ---------------------------------------------------------------------------
__global__ __launch_bounds__(256) void embed_kernel(
    const float* __restrict__ robot, const float* __restrict__ human,
    const float* __restrict__ wrW1, const float* __restrict__ wrb1,
    const float* __restrict__ wrW2, const float* __restrict__ wrb2,
    const float* __restrict__ whW1, const float* __restrict__ whb1,
    const float* __restrict__ whW2, const float* __restrict__ whb2,
    float* __restrict__ X)
{
  __shared__ float hs[16 * HIDv];   // 4 KB
  const int b  = blockIdx.x >> 2;
  const int rg = blockIdx.x & 3;    // nodes rg*16 .. rg*16+15
  const int t  = threadIdx.x;

  // phase 1: hidden layer for this block's 16 nodes (4 values/thread)
  for (int v = t; v < 16 * HIDv; v += 256) {
    const int nl = v >> 6, k = v & 63;
    const int n  = rg * 16 + nl;
    const float* W1; const float* b1; const float* in; int K;
    if (n == 0) { W1 = wrW1; b1 = wrb1; in = robot + b * RDim;                K = RDim; }
    else        { W1 = whW1; b1 = whb1; in = human + (b * 63 + n - 1) * HDim; K = HDim; }
    float acc = b1[k];
    for (int j = 0; j < K; ++j) acc = fmaf(in[j], W1[j * HIDv + k], acc);
    hs[v] = fmaxf(acc, 0.f);
  }
  __syncthreads();

  // phase 2: thread t -> dim d = t&127, nodes {2c + (t>>7)}, c=0..7 (local).
  // All nodes first computed with the HUMAN output layer; the 128 threads
  // owning global node 0 (rg==0, which==0, c==0) then recompute it with the
  // robot output layer.  Avoids per-iteration weight-pointer selection.
  const int d     = t & 127;
  const int which = t >> 7;

  float acc[8];
#pragma unroll
  for (int c = 0; c < 8; ++c) acc[c] = whb2[d];

  for (int k4 = 0; k4 < 16; ++k4) {
    float w4[4];
#pragma unroll
    for (int kk = 0; kk < 4; ++kk) w4[kk] = whW2[(4 * k4 + kk) * XDv + d];
#pragma unroll
    for (int c = 0; c < 8; ++c) {
      const float4 h4 = *reinterpret_cast<const float4*>(&hs[(2 * c + which) * HIDv + 4 * k4]);
      acc[c] = fmaf(h4.x, w4[0], acc[c]);
      acc[c] = fmaf(h4.y, w4[1], acc[c]);
      acc[c] = fmaf(h4.z, w4[2], acc[c]);
      acc[c] = fmaf(h4.w, w4[3], acc[c]);
    }
  }
  if (rg == 0 && which == 0) {        // redo node 0 with robot weights
    float a = wrb2[d];
#pragma unroll 8
    for (int k = 0; k < HIDv; ++k) a = fmaf(hs[k], wrW2[k * XDv + d], a);
    acc[0] = a;
  }
#pragma unroll
  for (int c = 0; c < 8; ++c) {
    const int n = rg * 16 + 2 * c + which;
    X[(size_t)(b * NN + n) * XDv + d] = fmaxf(acc[c], 0.f);
  }
}

// ---------------------------------------------------------------------------
// Kernel 2/4: per-node transform for a GAT layer.
//   Xin [8192,128] @ W1[256,256] -> UV [8192,512]
//   cols 0..255  : U' = Xin @ W1[0:128,:] + b1   (source-row term)
//   cols 256..511: V  = Xin @ W1[128:256,:]      (target-col term)
// Block: 256 threads, 16 nodes, thread t owns cols t and t+256.
// 512 blocks -> 2 blocks/CU; X rows broadcast from LDS (uniform -> no conflict).
// ---------------------------------------------------------------------------
__global__ __launch_bounds__(256) void transform_kernel(
    const float* __restrict__ Xin, const float* __restrict__ W1,
    const float* __restrict__ b1, float* __restrict__ UV)
{
  __shared__ float Xs[16 * XDv];  // 8 KB
  const int t = threadIdx.x;
  const int base = blockIdx.x * 16;

  for (int idx = t; idx < 16 * XDv / 4; idx += 256)
    *reinterpret_cast<float4*>(Xs + idx * 4) =
        *reinterpret_cast<const float4*>(Xin + (size_t)base * XDv + idx * 4);
  __syncthreads();

  float acc0[16], acc1[16];
  const float bias = b1[t];
#pragma unroll
  for (int n = 0; n < 16; ++n) { acc0[n] = bias; acc1[n] = 0.f; }

  for (int k = 0; k < XDv; k += 4) {
    float w0[4], w1[4];
#pragma unroll
    for (int kk = 0; kk < 4; ++kk) {
      w0[kk] = W1[(k + kk) * 256 + t];
      w1[kk] = W1[(128 + k + kk) * 256 + t];
    }
#pragma unroll
    for (int n = 0; n < 16; ++n) {
      const float4 x4 = *reinterpret_cast<const float4*>(&Xs[n * XDv + k]);
      acc0[n] = fmaf(x4.x, w0[0], acc0[n]);
      acc0[n] = fmaf(x4.y, w0[1], acc0[n]);
      acc0[n] = fmaf(x4.z, w0[2], acc0[n]);
      acc0[n] = fmaf(x4.w, w0[3], acc0[n]);
      acc1[n] = fmaf(x4.x, w1[0], acc1[n]);
      acc1[n] = fmaf(x4.y, w1[1], acc1[n]);
      acc1[n] = fmaf(x4.z, w1[2], acc1[n]);
      acc1[n] = fmaf(x4.w, w1[3], acc1[n]);
    }
  }
#pragma unroll
  for (int n = 0; n < 16; ++n) {
    UV[(size_t)(base + n) * 512 + t]       = acc0[n];
    UV[(size_t)(base + n) * 512 + 256 + t] = acc1[n];
  }
}

// ---------------------------------------------------------------------------
// Kernel 3/5: attention + PV (+ optional fused skip sum).
//   e[i,j] = leaky( sum_k relu(U'[i,k] + V[j,k]) * W2[k] + b2 ), mask col 0
//   attn = softmax_j, H[i] = attn @ Xpv ;  if add_skip: out = H + Xpv[i] + Xskip[i]
// Grid: 4 blocks per batch (16 rows each), 256 threads = 4 waves.
// LDS: static 64 KB exactly (2 blocks/CU).
// Phase A: V staged in LDS [64][256] with float4-chunk XOR swizzle
//          (chunk c of row j stored at c ^ (j&7): lane-j ds_read_b128 then
//           spreads the 8 j-groups over distinct bank quads -> b128 8-cycle
//           floor instead of a single-bank pileup).
//          U' rows + W2 read via wave-uniform global broadcast (L1/L2-hot).
//          Wave w computes rows 4w..4w+3; lane = j; softmax via shfl_xor.
// Phase B: LDS reused for Xpv rows + attn weights; thread = (d4, row-pair).
// ---------------------------------------------------------------------------
__global__ __launch_bounds__(256) void attn_kernel(
    const float* __restrict__ UV, const float* __restrict__ Xpv,
    const float* __restrict__ Xskip, const float* __restrict__ W2g,
    const float* __restrict__ b2g, float* __restrict__ out, int add_skip)
{
  __shared__ float smem[16384];        // 64 KB static
  float* Vsf = smem;                   // [64][256] swizzled

  const int b  = blockIdx.x >> 2;
  const int rg = blockIdx.x & 3;       // row group: rows rg*16 .. rg*16+15
  const int t  = threadIdx.x;
  const float* UVb = UV + (size_t)b * NN * 512;

  // stage V (swizzled)
  for (int cc = t; cc < NN * 64; cc += 256) {
    const int j = cc >> 6, c = cc & 63;
    const float4 v = *reinterpret_cast<const float4*>(UVb + j * 512 + 256 + (c << 2));
    *reinterpret_cast<float4*>(Vsf + j * 256 + ((c ^ (j & 7)) << 2)) = v;
  }
  __syncthreads();

  // ---- phase A: logits + softmax -------------------------------------
  const int wv = t >> 6;      // wave id, rows 4wv..4wv+3
  const int lane = t & 63;    // = j
  const int jx = lane & 7;

  float e[4] = {0.f, 0.f, 0.f, 0.f};
  const float* Up[4];
#pragma unroll
  for (int q = 0; q < 4; ++q)
    Up[q] = UVb + (size_t)(rg * 16 + 4 * wv + q) * 512;

#pragma unroll 2
  for (int c = 0; c < 64; ++c) {
    const float4 v4 = *reinterpret_cast<const float4*>(Vsf + lane * 256 + ((c ^ jx) << 2));
    const float4 w4 = *reinterpret_cast<const float4*>(W2g + (c << 2));  // uniform
#pragma unroll
    for (int q = 0; q < 4; ++q) {
      const float4 u4 = *reinterpret_cast<const float4*>(Up[q] + (c << 2));  // uniform
      e[q] = fmaf(fmaxf(u4.x + v4.x, 0.f), w4.x, e[q]);
      e[q] = fmaf(fmaxf(u4.y + v4.y, 0.f), w4.y, e[q]);
      e[q] = fmaf(fmaxf(u4.z + v4.z, 0.f), w4.z, e[q]);
      e[q] = fmaf(fmaxf(u4.w + v4.w, 0.f), w4.w, e[q]);
    }
  }

  const float bias2 = b2g[0];
  float att[4];
#pragma unroll
  for (int q = 0; q < 4; ++q) {
    float s = e[q] + bias2;
    s = s > 0.f ? s : NEG_SLOPE * s;                 // LeakyReLU(0.04)
    const int i_glob = rg * 16 + 4 * wv + q;
    if (i_glob > 0 && lane == 0) s = MASK_VAL;       // humans can't attend robot
    float m = s;
#pragma unroll
    for (int off = 32; off > 0; off >>= 1) m = fmaxf(m, __shfl_xor(m, off));
    const float p = __expf(s - m);
    float sum = p;
#pragma unroll
    for (int off = 32; off > 0; off >>= 1) sum += __shfl_xor(sum, off);
    att[q] = p / sum;
  }
  __syncthreads();   // everyone done reading Vsf

  // ---- phase B: H = attn @ Xpv  (LDS reused) -------------------------
  float* Xs = smem;            // [64][128] = 8192 floats
  float* As = smem + 8192;     // [16][64]  = 1024 floats
#pragma unroll
  for (int q = 0; q < 4; ++q) As[(4 * wv + q) * 64 + lane] = att[q];

  const float* Xb = Xpv + (size_t)b * NN * XDv;
  for (int idx = t; idx < NN * XDv / 4; idx += 256)
    *reinterpret_cast<float4*>(Xs + idx * 4) =
        *reinterpret_cast<const float4*>(Xb + idx * 4);
  __syncthreads();

  const int l32 = t & 31, grp = t >> 5;   // grp 0..7 -> rows grp, grp+8
  const int d4 = l32 << 2;
  float4 a0 = {0.f, 0.f, 0.f, 0.f}, a1 = {0.f, 0.f, 0.f, 0.f};
  for (int j = 0; j < NN; ++j) {
    const float4 x4 = *reinterpret_cast<const float4*>(Xs + j * XDv + d4);
    const float w0 = As[grp * 64 + j];
    const float w1 = As[(grp + 8) * 64 + j];
    a0.x = fmaf(w0, x4.x, a0.x); a0.y = fmaf(w0, x4.y, a0.y);
    a0.z = fmaf(w0, x4.z, a0.z); a0.w = fmaf(w0, x4.w, a0.w);
    a1.x = fmaf(w1, x4.x, a1.x); a1.y = fmaf(w1, x4.y, a1.y);
    a1.z = fmaf(w1, x4.z, a1.z); a1.w = fmaf(w1, x4.w, a1.w);
  }

  const int i0 = rg * 16 + grp, i1 = rg * 16 + grp + 8;
  if (add_skip) {   // out = H2 + H1 + X ; Xpv here IS H1 (staged in Xs)
    const float4 h0 = *reinterpret_cast<const float4*>(Xs + i0 * XDv + d4);
    const float4 h1 = *reinterpret_cast<const float4*>(Xs + i1 * XDv + d4);
    const float4 s0 = *reinterpret_cast<const float4*>(Xskip + ((size_t)b * NN + i0) * XDv + d4);
    const float4 s1 = *reinterpret_cast<const float4*>(Xskip + ((size_t)b * NN + i1) * XDv + d4);
    a0.x += h0.x + s0.x; a0.y += h0.y + s0.y; a0.z += h0.z + s0.z; a0.w += h0.w + s0.w;
    a1.x += h1.x + s1.x; a1.y += h1.y + s1.y; a1.z += h1.z + s1.z; a1.w += h1.w + s1.w;
  }
  *reinterpret_cast<float4*>(out + ((size_t)b * NN + i0) * XDv + d4) = a0;
  *reinterpret_cast<float4*>(out + ((size_t)b * NN + i1) * XDv + d4) = a1;
}

// ---------------------------------------------------------------------------
extern "C" void kernel_launch(void* const* d_in, const int* in_sizes, int n_in,
                              void* d_out, int out_size, void* d_ws, size_t ws_size,
                              hipStream_t stream) {
  const float* robot = (const float*)d_in[0];
  const float* human = (const float*)d_in[1];
  const float* wrW1  = (const float*)d_in[2];
  const float* wrb1  = (const float*)d_in[3];
  const float* wrW2  = (const float*)d_in[4];
  const float* wrb2  = (const float*)d_in[5];
  const float* whW1  = (const float*)d_in[6];
  const float* whb1  = (const float*)d_in[7];
  const float* whW2  = (const float*)d_in[8];
  const float* whb2  = (const float*)d_in[9];
  const float* g0W1  = (const float*)d_in[10];
  const float* g0b1  = (const float*)d_in[11];
  const float* g0W2  = (const float*)d_in[12];
  const float* g0b2  = (const float*)d_in[13];
  const float* g1W1  = (const float*)d_in[14];
  const float* g1b1  = (const float*)d_in[15];
  const float* g1W2  = (const float*)d_in[16];
  const float* g1b2  = (const float*)d_in[17];
  float* out = (float*)d_out;

  float* X   = (float*)d_ws;                       //  4 MB  [B,64,128]
  float* H1  = X  + (size_t)Bz * NN * XDv;         //  4 MB  [B,64,128]
  float* UVb = H1 + (size_t)Bz * NN * XDv;         // 16 MB  [B*64,512]

  embed_kernel<<<Bz * 4, 256, 0, stream>>>(robot, human, wrW1, wrb1, wrW2, wrb2,
                                           whW1, whb1, whW2, whb2, X);
  transform_kernel<<<Bz * NN / 16, 256, 0, stream>>>(X, g0W1, g0b1, UVb);
  attn_kernel<<<Bz * 4, 256, 0, stream>>>(UVb, X, nullptr, g0W2, g0b2, H1, 0);
  transform_kernel<<<Bz * NN / 16, 256, 0, stream>>>(H1, g1W1, g1b1, UVb);
  attn_kernel<<<Bz * 4, 256, 0, stream>>>(UVb, H1, X, g1W2, g1b2, out, 1);
}

// Round 8
// 174.070 us; speedup vs baseline: 1.1894x; 1.1894x over previous
//
#include <hip/hip_runtime.h>

#define NEG_SLOPE 0.04f
#define MASK_VAL  -9.0e15f

namespace {
constexpr int Bz = 128;   // batch
constexpr int NN = 64;    // nodes (1 robot + 63 humans)
constexpr int XD = 128;   // embedding dim
constexpr int HID = 64;   // embed hidden width
}

// ---------------------------------------------------------------------------
// Shared GAT layer body. Block = (batch b, row-half h: rows 32h..32h+31).
// 512 threads = 8 waves.  LDS (128 KB):
//   Ns [64][128]  node features (input to this layer)          [0,     8192)
//   Vs [64][256]  target-term, float4-chunk XOR swizzle        [8192, 24576)
//   Us [32][256]  source-term (this half's rows) -> later As   [24576,32768)
// Phases: T-V (all 64 nodes, wave w -> nodes 8w..8w+7, lane -> cols 4l..4l+3)
//         T-U (own 32 rows, wave w -> rows 4w..4w+3)
//         S   (scores, lane = j, rows 4w..4w+3; softmax via shfl_xor)
//         PV  (thread (grp,l32) -> rows grp,grp+16 at dims 4*l32..)
// Returns the two H-row float4s in o0/o1; caller writes/fuses them.
// ---------------------------------------------------------------------------
__device__ __forceinline__ void gat_layer(
    const float* __restrict__ Ns, float* __restrict__ Vs, float* __restrict__ UsAs,
    const float* __restrict__ W1, const float* __restrict__ b1,
    const float* __restrict__ W2, const float* __restrict__ b2,
    int h, int t, float4& o0, float4& o1)
{
  const int w = t >> 6, l = t & 63;

  // ---- T-V: V[n][c] = sum_k Ns[n][k] * W1[128+k][c]  (all 64 nodes) ----
  {
    float vac[8][4];
#pragma unroll
    for (int nn = 0; nn < 8; ++nn)
#pragma unroll
      for (int c = 0; c < 4; ++c) vac[nn][c] = 0.f;

    for (int ks = 0; ks < XD; ks += 4) {
      float wr[4][4];
#pragma unroll
      for (int kk = 0; kk < 4; ++kk) {
        const float4 wv = *reinterpret_cast<const float4*>(&W1[(XD + ks + kk) * 256 + (l << 2)]);
        wr[kk][0] = wv.x; wr[kk][1] = wv.y; wr[kk][2] = wv.z; wr[kk][3] = wv.w;
      }
#pragma unroll
      for (int nn = 0; nn < 8; ++nn) {
        const float4 x4 = *reinterpret_cast<const float4*>(&Ns[(8 * w + nn) * XD + ks]);
        const float xk0 = x4.x, xk1 = x4.y, xk2 = x4.z, xk3 = x4.w;
#pragma unroll
        for (int c = 0; c < 4; ++c) {
          vac[nn][c] = fmaf(xk0, wr[0][c], vac[nn][c]);
          vac[nn][c] = fmaf(xk1, wr[1][c], vac[nn][c]);
          vac[nn][c] = fmaf(xk2, wr[2][c], vac[nn][c]);
          vac[nn][c] = fmaf(xk3, wr[3][c], vac[nn][c]);
        }
      }
    }
#pragma unroll
    for (int nn = 0; nn < 8; ++nn) {
      const int n = 8 * w + nn;
      const float4 v = {vac[nn][0], vac[nn][1], vac[nn][2], vac[nn][3]};
      *reinterpret_cast<float4*>(&Vs[n * 256 + ((l ^ (n & 7)) << 2)]) = v;
    }
  }

  // ---- T-U: U'[r][c] = b1[c] + sum_k Ns[32h+r][k] * W1[k][c] (own rows) ----
  {
    float uac[4][4];
    const float4 bi = *reinterpret_cast<const float4*>(&b1[l << 2]);
#pragma unroll
    for (int q = 0; q < 4; ++q) { uac[q][0] = bi.x; uac[q][1] = bi.y; uac[q][2] = bi.z; uac[q][3] = bi.w; }

    for (int ks = 0; ks < XD; ks += 4) {
      float wr[4][4];
#pragma unroll
      for (int kk = 0; kk < 4; ++kk) {
        const float4 wv = *reinterpret_cast<const float4*>(&W1[(ks + kk) * 256 + (l << 2)]);
        wr[kk][0] = wv.x; wr[kk][1] = wv.y; wr[kk][2] = wv.z; wr[kk][3] = wv.w;
      }
#pragma unroll
      for (int q = 0; q < 4; ++q) {
        const float4 x4 = *reinterpret_cast<const float4*>(&Ns[(32 * h + 4 * w + q) * XD + ks]);
        const float xk0 = x4.x, xk1 = x4.y, xk2 = x4.z, xk3 = x4.w;
#pragma unroll
        for (int c = 0; c < 4; ++c) {
          uac[q][c] = fmaf(xk0, wr[0][c], uac[q][c]);
          uac[q][c] = fmaf(xk1, wr[1][c], uac[q][c]);
          uac[q][c] = fmaf(xk2, wr[2][c], uac[q][c]);
          uac[q][c] = fmaf(xk3, wr[3][c], uac[q][c]);
        }
      }
    }
#pragma unroll
    for (int q = 0; q < 4; ++q) {
      const float4 u = {uac[q][0], uac[q][1], uac[q][2], uac[q][3]};
      *reinterpret_cast<float4*>(&UsAs[(4 * w + q) * 256 + (l << 2)]) = u;
    }
  }
  __syncthreads();   // Vs + Us visible

  // ---- S: e[r][j] -> softmax -> att (lane = j) ----
  float att[4];
  {
    const int jx = l & 7;
    float e[4] = {0.f, 0.f, 0.f, 0.f};
    for (int c4 = 0; c4 < 64; ++c4) {
      const float4 v4 = *reinterpret_cast<const float4*>(&Vs[l * 256 + ((c4 ^ jx) << 2)]);
      const float4 w4 = *reinterpret_cast<const float4*>(&W2[c4 << 2]);   // uniform, L2-hot
#pragma unroll
      for (int q = 0; q < 4; ++q) {
        const float4 u4 = *reinterpret_cast<const float4*>(&UsAs[(4 * w + q) * 256 + (c4 << 2)]); // broadcast
        e[q] = fmaf(fmaxf(u4.x + v4.x, 0.f), w4.x, e[q]);
        e[q] = fmaf(fmaxf(u4.y + v4.y, 0.f), w4.y, e[q]);
        e[q] = fmaf(fmaxf(u4.z + v4.z, 0.f), w4.z, e[q]);
        e[q] = fmaf(fmaxf(u4.w + v4.w, 0.f), w4.w, e[q]);
      }
    }
    const float bias2 = b2[0];
#pragma unroll
    for (int q = 0; q < 4; ++q) {
      float s = e[q] + bias2;
      s = s > 0.f ? s : NEG_SLOPE * s;                 // LeakyReLU(0.04)
      const int gi = 32 * h + 4 * w + q;
      if (gi > 0 && l == 0) s = MASK_VAL;              // humans can't attend robot
      float m = s;
#pragma unroll
      for (int off = 32; off > 0; off >>= 1) m = fmaxf(m, __shfl_xor(m, off));
      const float p = __expf(s - m);
      float sum = p;
#pragma unroll
      for (int off = 32; off > 0; off >>= 1) sum += __shfl_xor(sum, off);
      att[q] = p / sum;
    }
  }
  __syncthreads();   // all Us reads done; region becomes As
#pragma unroll
  for (int q = 0; q < 4; ++q) UsAs[(4 * w + q) * 64 + l] = att[q];
  __syncthreads();

  // ---- PV: H[r] = att[r] @ Ns ----
  {
    const int grp = t >> 5, d4 = (t & 31) << 2;
    float4 a0 = {0.f, 0.f, 0.f, 0.f}, a1 = {0.f, 0.f, 0.f, 0.f};
    for (int j = 0; j < NN; ++j) {
      const float4 x4 = *reinterpret_cast<const float4*>(&Ns[j * XD + d4]);
      const float wA = UsAs[grp * 64 + j];
      const float wB = UsAs[(grp + 16) * 64 + j];
      a0.x = fmaf(wA, x4.x, a0.x); a0.y = fmaf(wA, x4.y, a0.y);
      a0.z = fmaf(wA, x4.z, a0.z); a0.w = fmaf(wA, x4.w, a0.w);
      a1.x = fmaf(wB, x4.x, a1.x); a1.y = fmaf(wB, x4.y, a1.y);
      a1.z = fmaf(wB, x4.z, a1.z); a1.w = fmaf(wB, x4.w, a1.w);
    }
    o0 = a0; o1 = a1;
  }
}

// ---------------------------------------------------------------------------
// Kernel 1: embed (all 64 nodes -> LDS Xs + global X) + GAT layer 1 -> H1g.
// ---------------------------------------------------------------------------
__global__ __launch_bounds__(512) void layer1_kernel(
    const float* __restrict__ robot, const float* __restrict__ human,
    const float* __restrict__ wrW1, const float* __restrict__ wrb1,
    const float* __restrict__ wrW2, const float* __restrict__ wrb2,
    const float* __restrict__ whW1, const float* __restrict__ whb1,
    const float* __restrict__ whW2, const float* __restrict__ whb2,
    const float* __restrict__ W1, const float* __restrict__ b1,
    const float* __restrict__ W2, const float* __restrict__ b2,
    float* __restrict__ Xg, float* __restrict__ H1g)
{
  __shared__ float smem[32768];        // 128 KB
  float* Xs = smem;                    // [64][128]
  float* Vs = smem + 8192;             // [64][256] swizzled
  float* Us = smem + 24576;            // [32][256]; pre-transform alias: hs[64][64]
  float* hs = smem + 24576;

  const int b = blockIdx.x >> 1, h = blockIdx.x & 1;
  const int t = threadIdx.x;

  // ---- E1: hidden layer, 64 nodes x 64 (n uniform per wave-iteration) ----
  for (int v = t; v < NN * HID; v += 512) {
    const int n = v >> 6, k = v & 63;
    float acc;
    if (n == 0) {
      acc = wrb1[k];
      for (int j = 0; j < 9; ++j) acc = fmaf(robot[b * 9 + j], wrW1[j * HID + k], acc);
    } else {
      const float* in = human + (b * 63 + n - 1) * 5;
      acc = whb1[k];
      for (int j = 0; j < 5; ++j) acc = fmaf(in[j], whW1[j * HID + k], acc);
    }
    hs[v] = fmaxf(acc, 0.f);
  }
  __syncthreads();

  // ---- E2: output layer; thread (d = t&127, which = t>>7), nodes 4c+which ----
  {
    const int d = t & 127, which = t >> 7;
    float xacc[16];
#pragma unroll
    for (int c = 0; c < 16; ++c) xacc[c] = whb2[d];

    for (int k4 = 0; k4 < 16; ++k4) {
      float w4[4];
#pragma unroll
      for (int kk = 0; kk < 4; ++kk) w4[kk] = whW2[(4 * k4 + kk) * XD + d];
#pragma unroll
      for (int c = 0; c < 16; ++c) {
        const float4 h4 = *reinterpret_cast<const float4*>(&hs[(4 * c + which) * HID + 4 * k4]);
        xacc[c] = fmaf(h4.x, w4[0], xacc[c]);
        xacc[c] = fmaf(h4.y, w4[1], xacc[c]);
        xacc[c] = fmaf(h4.z, w4[2], xacc[c]);
        xacc[c] = fmaf(h4.w, w4[3], xacc[c]);
      }
    }
    if (which == 0) {                  // redo global node 0 with robot weights
      float a = wrb2[d];
#pragma unroll 8
      for (int k = 0; k < HID; ++k) a = fmaf(hs[k], wrW2[k * XD + d], a);
      xacc[0] = a;
    }
#pragma unroll
    for (int c = 0; c < 16; ++c) {
      const int n = 4 * c + which;
      const float val = fmaxf(xacc[c], 0.f);
      Xs[n * XD + d] = val;
      if ((n >> 5) == h) Xg[((size_t)(b * NN + n)) * XD + d] = val;   // halves split the write
    }
  }
  __syncthreads();

  float4 a0, a1;
  gat_layer(Xs, Vs, Us, W1, b1, W2, b2, h, t, a0, a1);

  const int grp = t >> 5, d4 = (t & 31) << 2;
  const int n0 = 32 * h + grp, n1 = n0 + 16;
  *reinterpret_cast<float4*>(&H1g[((size_t)(b * NN + n0)) * XD + d4]) = a0;
  *reinterpret_cast<float4*>(&H1g[((size_t)(b * NN + n1)) * XD + d4]) = a1;
}

// ---------------------------------------------------------------------------
// Kernel 2: stage H1 -> GAT layer 2 -> out = H2 + H1 + X (skip fused).
// ---------------------------------------------------------------------------
__global__ __launch_bounds__(512) void layer2_kernel(
    const float* __restrict__ H1g, const float* __restrict__ Xg,
    const float* __restrict__ W1, const float* __restrict__ b1,
    const float* __restrict__ W2, const float* __restrict__ b2,
    float* __restrict__ out)
{
  __shared__ float smem[32768];
  float* Ys = smem;                    // [64][128] = staged H1
  float* Vs = smem + 8192;
  float* Us = smem + 24576;

  const int b = blockIdx.x >> 1, h = blockIdx.x & 1;
  const int t = threadIdx.x;

  const float* Hb = H1g + (size_t)b * NN * XD;
  for (int idx = t; idx < NN * XD / 4; idx += 512)
    *reinterpret_cast<float4*>(Ys + idx * 4) =
        *reinterpret_cast<const float4*>(Hb + idx * 4);
  __syncthreads();

  float4 a0, a1;
  gat_layer(Ys, Vs, Us, W1, b1, W2, b2, h, t, a0, a1);

  const int grp = t >> 5, d4 = (t & 31) << 2;
  const int n0 = 32 * h + grp, n1 = n0 + 16;
  const float4 y0 = *reinterpret_cast<const float4*>(&Ys[n0 * XD + d4]);
  const float4 y1 = *reinterpret_cast<const float4*>(&Ys[n1 * XD + d4]);
  const float4 x0 = *reinterpret_cast<const float4*>(&Xg[((size_t)(b * NN + n0)) * XD + d4]);
  const float4 x1 = *reinterpret_cast<const float4*>(&Xg[((size_t)(b * NN + n1)) * XD + d4]);
  a0.x += y0.x + x0.x; a0.y += y0.y + x0.y; a0.z += y0.z + x0.z; a0.w += y0.w + x0.w;
  a1.x += y1.x + x1.x; a1.y += y1.y + x1.y; a1.z += y1.z + x1.z; a1.w += y1.w + x1.w;
  *reinterpret_cast<float4*>(&out[((size_t)(b * NN + n0)) * XD + d4]) = a0;
  *reinterpret_cast<float4*>(&out[((size_t)(b * NN + n1)) * XD + d4]) = a1;
}

// ---------------------------------------------------------------------------
extern "C" void kernel_launch(void* const* d_in, const int* in_sizes, int n_in,
                              void* d_out, int out_size, void* d_ws, size_t ws_size,
                              hipStream_t stream) {
  const float* robot = (const float*)d_in[0];
  const float* human = (const float*)d_in[1];
  const float* wrW1  = (const float*)d_in[2];
  const float* wrb1  = (const float*)d_in[3];
  const float* wrW2  = (const float*)d_in[4];
  const float* wrb2  = (const float*)d_in[5];
  const float* whW1  = (const float*)d_in[6];
  const float* whb1  = (const float*)d_in[7];
  const float* whW2  = (const float*)d_in[8];
  const float* whb2  = (const float*)d_in[9];
  const float* g0W1  = (const float*)d_in[10];
  const float* g0b1  = (const float*)d_in[11];
  const float* g0W2  = (const float*)d_in[12];
  const float* g0b2  = (const float*)d_in[13];
  const float* g1W1  = (const float*)d_in[14];
  const float* g1b1  = (const float*)d_in[15];
  const float* g1W2  = (const float*)d_in[16];
  const float* g1b2  = (const float*)d_in[17];
  float* out = (float*)d_out;

  float* Xg  = (float*)d_ws;                       // 4 MB [B,64,128]
  float* H1g = Xg + (size_t)Bz * NN * XD;          // 4 MB [B,64,128]

  layer1_kernel<<<Bz * 2, 512, 0, stream>>>(robot, human, wrW1, wrb1, wrW2, wrb2,
                                            whW1, whb1, whW2, whb2,
                                            g0W1, g0b1, g0W2, g0b2, Xg, H1g);
  layer2_kernel<<<Bz * 2, 512, 0, stream>>>(H1g, Xg, g1W1, g1b1, g1W2, g1b2, out);
}